// Round 7
// baseline (997.439 us; speedup 1.0000x reference)
//
#include <hip/hip_runtime.h>

// GCN layer: out = A_coo @ (X @ W) + b
// N=100000 nodes, E=3200000 edges, D_IN=D_OUT=256.
//
// R10: global src-bucket sweep with register accumulators.
// Evidence chain: R3/R5/R6/R9 all plateau at 3.83-3.93 TB/s, FETCH 764-771MB
// (53% L2 miss == random working set vs ~24MB effective L2). R9 proved
// per-node ordering can't shrink the window (32 edges/node, batch spans
// half of src space). R8 proved LDS fp atomics are fatal (~80cy/op).
// Fix: edges sorted by (src-bucket, dst-wavegroup); 2048 waves ALL resident
// (512 blocks x 4 waves, 2 blocks/CU) sweep 32 buckets in lockstep-ish;
// each wave owns 49 nodes' acc in VGPRs (196 regs); per-edge node index is
// WAVE-UNIFORM -> scalar switch, no runtime VGPR indexing, no LDS.
// Predicted: aggregate FETCH 764->~450MB, dur 231->~140us.

typedef __bf16 bf16;
typedef bf16 bf16x4 __attribute__((ext_vector_type(4)));
typedef bf16 bf16x8 __attribute__((ext_vector_type(8)));
typedef float f32x4 __attribute__((ext_vector_type(4)));
typedef int i32x2 __attribute__((ext_vector_type(2)));

#define D_DIM 256
#define NB 32          // src buckets (1.6MB of S each)
#define NGRP 2048      // dst wavegroups (= resident waves)
#define G 49           // dst nodes per wavegroup (2041 groups used)

__device__ __forceinline__ int bucket_of(unsigned s, unsigned magic) {
    unsigned b = (unsigned)(((unsigned long long)s * magic) >> 32);
    return b > (NB - 1) ? (NB - 1) : (int)b;
}
__device__ __forceinline__ int wgroup_of(unsigned d, unsigned m49) {
    return (int)(((unsigned long long)d * m49) >> 32);   // exact floor(d/49) for d<2^20
}

// ---- 1) pack W[256][256] fp32 -> bf16 MFMA B-fragment layout ----
__global__ void pack_w(const float* __restrict__ W, bf16* __restrict__ Wf) {
    int lane = threadIdx.x;           // 64
    int blk  = blockIdx.x;            // 128 = 8 kt * 16 nt
    int kt = blk >> 4, nt = blk & 15;
    int t = lane & 15, q = lane >> 4;
    int krow = kt * 32 + q * 8;
    int col  = nt * 16 + t;
    bf16x8 v;
#pragma unroll
    for (int j = 0; j < 8; ++j)
        v[j] = (bf16)W[(size_t)(krow + j) * D_DIM + col];
    ((bf16x8*)Wf)[(size_t)blk * 64 + lane] = v;
}

// ---- 2) GEMM: support = X @ W (bf16 out). One wave = 16 rows x 256 cols ----
__global__ void gemm_xw(const float* __restrict__ X, const bf16* __restrict__ Wf,
                        bf16* __restrict__ S, int N) {
    int wid  = blockIdx.x * 4 + (threadIdx.x >> 6);
    int base = wid * 16;
    if (base >= N) return;
    int lane = threadIdx.x & 63;
    int t = lane & 15, q = lane >> 4;

    const float* xrow = X + (size_t)(base + t) * D_DIM + q * 8;
    const bf16x8* wf = (const bf16x8*)Wf;

    f32x4 acc[16];
#pragma unroll
    for (int i = 0; i < 16; ++i) acc[i] = (f32x4){0.f, 0.f, 0.f, 0.f};

#pragma unroll
    for (int kt = 0; kt < 8; ++kt) {
        f32x4 x0 = *(const f32x4*)(xrow + kt * 32);
        f32x4 x1 = *(const f32x4*)(xrow + kt * 32 + 4);
        bf16x8 a;
        a[0] = (bf16)x0[0]; a[1] = (bf16)x0[1]; a[2] = (bf16)x0[2]; a[3] = (bf16)x0[3];
        a[4] = (bf16)x1[0]; a[5] = (bf16)x1[1]; a[6] = (bf16)x1[2]; a[7] = (bf16)x1[3];
#pragma unroll
        for (int nt = 0; nt < 16; ++nt) {
            bf16x8 bfr = wf[(size_t)(kt * 16 + nt) * 64 + lane];
            acc[nt] = __builtin_amdgcn_mfma_f32_16x16x32_bf16(a, bfr, acc[nt], 0, 0, 0);
        }
    }

#pragma unroll
    for (int nt = 0; nt < 16; ++nt) {
#pragma unroll
        for (int r = 0; r < 4; ++r) {
            S[(size_t)(base + q * 4 + r) * D_DIM + nt * 16 + t] = (bf16)acc[nt][r];
        }
    }
}

// ---- 3a) histogram + rank over 65536 (bucket,group) keys. 8 edges/thread ----
__global__ void rank4(const int* __restrict__ esrc, const int* __restrict__ edst,
                      int* __restrict__ cnt, int* __restrict__ erank, int E,
                      unsigned bmagic, unsigned m49) {
    int gid  = blockIdx.x * blockDim.x + threadIdx.x;
    int base = gid * 8;
    if (base + 8 <= E) {
        int4 s0 = *(const int4*)(esrc + base);
        int4 s1 = *(const int4*)(esrc + base + 4);
        int4 d0 = *(const int4*)(edst + base);
        int4 d1 = *(const int4*)(edst + base + 4);
        int4 r0, r1;
        r0.x = atomicAdd(&cnt[bucket_of(s0.x, bmagic) * NGRP + wgroup_of(d0.x, m49)], 1);
        r0.y = atomicAdd(&cnt[bucket_of(s0.y, bmagic) * NGRP + wgroup_of(d0.y, m49)], 1);
        r0.z = atomicAdd(&cnt[bucket_of(s0.z, bmagic) * NGRP + wgroup_of(d0.z, m49)], 1);
        r0.w = atomicAdd(&cnt[bucket_of(s0.w, bmagic) * NGRP + wgroup_of(d0.w, m49)], 1);
        r1.x = atomicAdd(&cnt[bucket_of(s1.x, bmagic) * NGRP + wgroup_of(d1.x, m49)], 1);
        r1.y = atomicAdd(&cnt[bucket_of(s1.y, bmagic) * NGRP + wgroup_of(d1.y, m49)], 1);
        r1.z = atomicAdd(&cnt[bucket_of(s1.z, bmagic) * NGRP + wgroup_of(d1.z, m49)], 1);
        r1.w = atomicAdd(&cnt[bucket_of(s1.w, bmagic) * NGRP + wgroup_of(d1.w, m49)], 1);
        *(int4*)(erank + base)     = r0;
        *(int4*)(erank + base + 4) = r1;
    } else {
        for (int e = base; e < E; ++e)
            erank[e] = atomicAdd(
                &cnt[bucket_of(esrc[e], bmagic) * NGRP + wgroup_of(edst[e], m49)], 1);
    }
}

// ---- 3b) per-block exclusive scan (1024 elems/block) ----
__global__ void scan_block(const int* __restrict__ counts, int n,
                           int* __restrict__ local_ex, int* __restrict__ bsums) {
    __shared__ int lds[1024];
    int tid = threadIdx.x;
    int g = blockIdx.x * 1024 + tid;
    int v = (g < n) ? counts[g] : 0;
    lds[tid] = v;
    __syncthreads();
    for (int d = 1; d < 1024; d <<= 1) {
        int add = (tid >= d) ? lds[tid - d] : 0;
        __syncthreads();
        lds[tid] += add;
        __syncthreads();
    }
    if (g < n) local_ex[g] = lds[tid] - v;
    if (tid == 1023) bsums[blockIdx.x] = lds[tid];
}

// ---- 3c) scan of block sums (single block, nb <= 128) ----
__global__ void scan_sums(const int* __restrict__ bsums, int nb, int* __restrict__ bex) {
    __shared__ int lds[128];
    int tid = threadIdx.x;
    int v = (tid < nb) ? bsums[tid] : 0;
    lds[tid] = v;
    __syncthreads();
    for (int d = 1; d < 128; d <<= 1) {
        int add = (tid >= d) ? lds[tid - d] : 0;
        __syncthreads();
        lds[tid] += add;
        __syncthreads();
    }
    if (tid < nb) bex[tid] = lds[tid] - v;
}

// ---- 3d) add block base; also writes sentinel off[n] = E ----
__global__ void add_base(int* __restrict__ off, const int* __restrict__ bex,
                         int n, int E) {
    int g = blockIdx.x * 1024 + threadIdx.x;
    if (g < n) off[g] += bex[blockIdx.x];
    if (g == 0) off[n] = E;
}

// ---- 3e) scatter (ATOMIC-FREE): pos = off[key] + rank; payload packs dloc ----
__global__ void scatter4(const int* __restrict__ esrc, const int* __restrict__ edst,
                         const float* __restrict__ evals, const int* __restrict__ erank,
                         const int* __restrict__ off, i32x2* __restrict__ eP, int E,
                         unsigned bmagic, unsigned m49) {
    int gid  = blockIdx.x * blockDim.x + threadIdx.x;
    int base = gid * 8;
    if (base + 8 <= E) {
        int4 s0 = *(const int4*)(esrc + base);
        int4 s1 = *(const int4*)(esrc + base + 4);
        int4 d0 = *(const int4*)(edst + base);
        int4 d1 = *(const int4*)(edst + base + 4);
        int4 r0 = *(const int4*)(erank + base);
        int4 r1 = *(const int4*)(erank + base + 4);
        float4 v0 = *(const float4*)(evals + base);
        float4 v1 = *(const float4*)(evals + base + 4);
        int ss[8] = {s0.x, s0.y, s0.z, s0.w, s1.x, s1.y, s1.z, s1.w};
        int dd[8] = {d0.x, d0.y, d0.z, d0.w, d1.x, d1.y, d1.z, d1.w};
        int rr[8] = {r0.x, r0.y, r0.z, r0.w, r1.x, r1.y, r1.z, r1.w};
        float vv[8] = {v0.x, v0.y, v0.z, v0.w, v1.x, v1.y, v1.z, v1.w};
#pragma unroll
        for (int j = 0; j < 8; ++j) {
            int wg = wgroup_of(dd[j], m49);
            int dl = dd[j] - wg * G;
            int key = bucket_of(ss[j], bmagic) * NGRP + wg;
            int pos = off[key] + rr[j];
            eP[pos] = (i32x2){ss[j] | (dl << 20), __float_as_int(vv[j])};
        }
    } else {
        for (int e = base; e < E; ++e) {
            int wg = wgroup_of(edst[e], m49);
            int dl = edst[e] - wg * G;
            int key = bucket_of(esrc[e], bmagic) * NGRP + wg;
            int pos = off[key] + erank[e];
            eP[pos] = (i32x2){esrc[e] | (dl << 20), __float_as_int(evals[e])};
        }
    }
}

// ---- 4) aggregate4: 2048 resident waves sweep 32 src-buckets together.
// Wave owns G=49 nodes, acc in VGPRs; per-edge node index is wave-uniform
// -> scalar switch. Lane owns cols [lane*4, lane*4+4).
#define APPLY(P, V) {                                                        \
    unsigned px = (unsigned)(P)[0];                                          \
    float wt = __int_as_float((P)[1]);                                       \
    float f0 = wt * (float)(V)[0], f1 = wt * (float)(V)[1],                  \
          f2 = wt * (float)(V)[2], f3 = wt * (float)(V)[3];                  \
    switch (px >> 20) {                                                      \
        CASE(0) CASE(1) CASE(2) CASE(3) CASE(4) CASE(5) CASE(6) CASE(7)      \
        CASE(8) CASE(9) CASE(10) CASE(11) CASE(12) CASE(13) CASE(14)         \
        CASE(15) CASE(16) CASE(17) CASE(18) CASE(19) CASE(20) CASE(21)       \
        CASE(22) CASE(23) CASE(24) CASE(25) CASE(26) CASE(27) CASE(28)       \
        CASE(29) CASE(30) CASE(31) CASE(32) CASE(33) CASE(34) CASE(35)       \
        CASE(36) CASE(37) CASE(38) CASE(39) CASE(40) CASE(41) CASE(42)       \
        CASE(43) CASE(44) CASE(45) CASE(46) CASE(47) CASE(48)                \
    } }
#define CASE(i) case i: acc[i][0]+=f0; acc[i][1]+=f1; acc[i][2]+=f2; acc[i][3]+=f3; break;

__global__ void __launch_bounds__(256, 2) aggregate4(
        const bf16* __restrict__ S, const int* __restrict__ off4,
        const i32x2* __restrict__ eP, const float* __restrict__ b,
        float* __restrict__ out, int N) {
    int wid  = threadIdx.x >> 6;
    int lane = threadIdx.x & 63;
    int w    = blockIdx.x * 4 + wid;        // 0..2047 == wavegroup id

    const f32x4 bias = ((const f32x4*)b)[lane];
    f32x4 acc[G];
#pragma unroll
    for (int i = 0; i < G; ++i) acc[i] = bias;

    for (int k = 0; k < NB; ++k) {
        int s = off4[k * NGRP + w];
        int t = off4[k * NGRP + w + 1];
        int e = s;
        for (; e + 4 <= t; e += 4) {
            i32x2 p0 = eP[e], p1 = eP[e + 1], p2 = eP[e + 2], p3 = eP[e + 3];
            bf16x4 v0 = *((const bf16x4*)(S + (size_t)(p0[0] & 0xFFFFF) * D_DIM) + lane);
            bf16x4 v1 = *((const bf16x4*)(S + (size_t)(p1[0] & 0xFFFFF) * D_DIM) + lane);
            bf16x4 v2 = *((const bf16x4*)(S + (size_t)(p2[0] & 0xFFFFF) * D_DIM) + lane);
            bf16x4 v3 = *((const bf16x4*)(S + (size_t)(p3[0] & 0xFFFFF) * D_DIM) + lane);
            APPLY(p0, v0) APPLY(p1, v1) APPLY(p2, v2) APPLY(p3, v3)
        }
        for (; e < t; ++e) {
            i32x2 p = eP[e];
            bf16x4 v = *((const bf16x4*)(S + (size_t)(p[0] & 0xFFFFF) * D_DIM) + lane);
            APPLY(p, v)
        }
    }

#pragma unroll
    for (int i = 0; i < G; ++i) {
        int node = w * G + i;
        if (node < N)
            __builtin_nontemporal_store(acc[i], (f32x4*)out + (size_t)node * 64 + lane);
    }
}

extern "C" void kernel_launch(void* const* d_in, const int* in_sizes, int n_in,
                              void* d_out, int out_size, void* d_ws, size_t ws_size,
                              hipStream_t stream) {
    const float* X     = (const float*)d_in[0];
    const int*   esrc  = (const int*)d_in[1];
    const int*   edst  = (const int*)d_in[2];
    const float* evals = (const float*)d_in[3];
    const float* W     = (const float*)d_in[4];
    const float* bias  = (const float*)d_in[5];
    float* out = (float*)d_out;

    const int N = in_sizes[0] / D_DIM;   // 100000
    const int E = in_sizes[1];           // 3200000

    const int M2 = NB * NGRP;            // 65536 keys
    // bucket(src) = hi32(src * bmagic) ~ src*NB/N, clamped
    const unsigned bmagic = (unsigned)((((unsigned long long)NB << 32) + N - 1) / N);
    // wgroup(dst) = hi32(dst * m49) = floor(dst/G) exactly for dst < 2^20
    const unsigned m49 = (unsigned)((((unsigned long long)1 << 32) + G - 1) / G);

    // workspace carve-up (256B aligned)
    auto alignup = [](size_t x) { return (x + 255) & ~(size_t)255; };
    char* ws = (char*)d_ws;
    size_t o = 0;
    bf16* S      = (bf16*)(ws + o); o = alignup(o + (size_t)N * D_DIM * sizeof(bf16));
    int* cnt4    = (int*)(ws + o);  o = alignup(o + (size_t)(M2 + 16) * sizeof(int));
    int* off4    = (int*)(ws + o);  o = alignup(o + (size_t)(M2 + 16) * sizeof(int));
    int* erank   = (int*)(ws + o);  o = alignup(o + (size_t)E * sizeof(int));
    int* bsums   = (int*)(ws + o);  o = alignup(o + 1024 * sizeof(int));
    int* bex     = (int*)(ws + o);  o = alignup(o + 1024 * sizeof(int));
    i32x2* eP    = (i32x2*)(ws + o); o = alignup(o + (size_t)E * sizeof(i32x2));
    bf16* Wf     = (bf16*)(ws + o); o = alignup(o + (size_t)D_DIM * D_DIM * sizeof(bf16));

    const int nwaves = (N + 15) / 16;              // gemm waves
    const int nb8    = ((E + 7) / 8 + 255) / 256;  // blocks for 8-edge kernels
    const int nbs    = (M2 + 1023) / 1024;         // 64 scan blocks (<=128)

    hipMemsetAsync(cnt4, 0, (size_t)(M2 + 16) * sizeof(int), stream);
    pack_w<<<128, 64, 0, stream>>>(W, Wf);
    gemm_xw<<<(nwaves + 3) / 4, 256, 0, stream>>>(X, Wf, S, N);
    rank4<<<nb8, 256, 0, stream>>>(esrc, edst, cnt4, erank, E, bmagic, m49);
    scan_block<<<nbs, 1024, 0, stream>>>(cnt4, M2, off4, bsums);
    scan_sums<<<1, 128, 0, stream>>>(bsums, nbs, bex);
    add_base<<<nbs, 1024, 0, stream>>>(off4, bex, M2, E);
    scatter4<<<nb8, 256, 0, stream>>>(esrc, edst, evals, erank, off4, eP, E, bmagic, m49);
    aggregate4<<<NGRP / 4, 256, 0, stream>>>(S, off4, eP, bias, out, N);
}